// Round 11
// baseline (416.941 us; speedup 1.0000x reference)
//
#include <hip/hip_runtime.h>
#include <hip/hip_bf16.h>

#define THREADS 256
#define NREP 8             // XCD-local replicas for count/cursor

typedef __attribute__((ext_vector_type(8))) short s16x8;   // 8 bf16 = 4 VGPR
typedef __attribute__((ext_vector_type(4))) float f32x4;

// bf16 helpers (RNE)
static __device__ __forceinline__ unsigned short f2bf(float f) {
  union { float f; unsigned u; } v; v.f = f;
  unsigned r = (v.u + 0x7FFF + ((v.u >> 16) & 1)) >> 16;
  return (unsigned short)r;
}
static __device__ __forceinline__ float bf2f(unsigned short h) {
  union { unsigned u; float f; } v; v.u = ((unsigned)h) << 16;
  return v.f;
}

// ---------- CSR build ----------
__global__ void k_init8(int* cnt8_s, int* cnt8_f, int n8) {
  for (int i = blockIdx.x * blockDim.x + threadIdx.x; i < n8; i += gridDim.x * blockDim.x) {
    cnt8_s[i] = 0; cnt8_f[i] = 0;
  }
}

// one int32 atomic per edge into the blockIdx&7 replica
__global__ void k_cnt(const int* __restrict__ col_s, const int* __restrict__ col_f,
                      int* cnt8_s, int* cnt8_f, int E, int N) {
  const int* col = blockIdx.y ? col_f : col_s;
  int*       cnt = blockIdx.y ? cnt8_f : cnt8_s;
  int g = blockIdx.x & (NREP - 1);
  int e = blockIdx.x * blockDim.x + threadIdx.x;
  if (e < E) atomicAdd(&cnt[(size_t)g * N + col[e]], 1);
}

// ---------- parallel exclusive scan over 8N keys (c-major: key = c*8+g) ----------
__global__ void k_scan1(const int* __restrict__ cnt8_s, const int* __restrict__ cnt8_f,
                        int* __restrict__ rp8_s, int* __restrict__ rp8_f,
                        int* __restrict__ bsum, int N, int nb8) {
  const int* cnt = blockIdx.y ? cnt8_f : cnt8_s;
  int*       rp  = blockIdx.y ? rp8_f  : rp8_s;
  int nk = N * NREP;
  __shared__ int buf[THREADS];
  int idx = blockIdx.x * THREADS + threadIdx.x;
  int v = 0;
  if (idx < nk) {
    int c = idx >> 3, g = idx & 7;
    v = cnt[(size_t)g * N + c];
  }
  buf[threadIdx.x] = v;
  __syncthreads();
  #pragma unroll
  for (int off = 1; off < THREADS; off <<= 1) {
    int t = (threadIdx.x >= off) ? buf[threadIdx.x - off] : 0;
    __syncthreads();
    buf[threadIdx.x] += t;
    __syncthreads();
  }
  if (idx < nk) rp[idx] = buf[threadIdx.x] - v;          // block-local exclusive
  if (threadIdx.x == THREADS - 1) bsum[blockIdx.y * nb8 + blockIdx.x] = buf[THREADS - 1];
}

// looped single-block scan of the nb8 block sums (per graph)
__global__ void k_scan2(int* __restrict__ bsum, int nb8) {
  int* b = bsum + blockIdx.x * nb8;
  __shared__ int buf[THREADS];
  __shared__ int carry;
  if (threadIdx.x == 0) carry = 0;
  __syncthreads();
  for (int base = 0; base < nb8; base += THREADS) {
    int i = base + threadIdx.x;
    int v = (i < nb8) ? b[i] : 0;
    buf[threadIdx.x] = v;
    __syncthreads();
    #pragma unroll
    for (int off = 1; off < THREADS; off <<= 1) {
      int t = (threadIdx.x >= off) ? buf[threadIdx.x - off] : 0;
      __syncthreads();
      buf[threadIdx.x] += t;
      __syncthreads();
    }
    if (i < nb8) b[i] = carry + buf[threadIdx.x] - v;   // exclusive
    __syncthreads();
    if (threadIdx.x == 0) carry += buf[THREADS - 1];
    __syncthreads();
  }
}

// add block offsets; rowptr (c-major) and cursor (replica-major); rp8[8N] = E
__global__ void k_scan3(int* __restrict__ rp8_s, int* __restrict__ rp8_f,
                        int* __restrict__ cur8_s, int* __restrict__ cur8_f,
                        const int* __restrict__ bsum, int N, int nb8, int E) {
  int* rp  = blockIdx.y ? rp8_f  : rp8_s;
  int* cur = blockIdx.y ? cur8_f : cur8_s;
  const int* bs = bsum + blockIdx.y * nb8;
  int nk = N * NREP;
  int idx = blockIdx.x * THREADS + threadIdx.x;
  if (idx < nk) {
    int pos = rp[idx] + bs[blockIdx.x];
    rp[idx] = pos;
    cur[(size_t)(idx & 7) * N + (idx >> 3)] = pos;
  }
  if (idx == 0) rp[nk] = E;
}

// 4-byte edge record: src (low 16) | bf16(raw w) (high 16). No dis needed here.
__global__ void k_scatter2(const int* __restrict__ ei_s, const float* __restrict__ w_s,
                           const int* __restrict__ ei_f, const float* __restrict__ w_f,
                           int* __restrict__ cur8_s, int* __restrict__ cur8_f,
                           unsigned* __restrict__ ed_s, unsigned* __restrict__ ed_f,
                           int E, int N) {
  const int*   ei  = blockIdx.y ? ei_f  : ei_s;
  const float* w   = blockIdx.y ? w_f   : w_s;
  int*         cur = blockIdx.y ? cur8_f : cur8_s;
  unsigned*    ed  = blockIdx.y ? ed_f  : ed_s;
  int g = blockIdx.x & (NREP - 1);
  int e = blockIdx.x * blockDim.x + threadIdx.x;
  if (e < E) {
    int r = ei[e];
    int c = ei[E + e];
    int pos = atomicAdd(&cur[(size_t)g * N + c], 1);
    ed[pos] = (unsigned)r | ((unsigned)f2bf(w[e]) << 16);
  }
}

// weighted degree via coalesced segmented sum over CSR; dis = rsqrt(1 + Σw)
__global__ void k_deg(const int* __restrict__ rp8_s, const unsigned* __restrict__ ed_s,
                      const int* __restrict__ rp8_f, const unsigned* __restrict__ ed_f,
                      float* __restrict__ dis_s, float* __restrict__ dis_f, int N) {
  const int*      rp  = blockIdx.y ? rp8_f : rp8_s;
  const unsigned* ed  = blockIdx.y ? ed_f  : ed_s;
  float*          dis = blockIdx.y ? dis_f : dis_s;
  int v = blockIdx.x * blockDim.x + threadIdx.x;
  if (v < N) {
    int e0 = rp[v * 8], e1 = rp[v * 8 + 8];
    float s = 0.f;
    for (int e = e0; e < e1; ++e) s += bf2f((unsigned short)(ed[e] >> 16));
    dis[v] = rsqrtf(1.0f + s);
  }
}

// ---------- cast x (f32) -> bf16 ----------
__global__ void k_cast(const float* __restrict__ in, unsigned short* __restrict__ out, int total4) {
  for (int i = blockIdx.x * blockDim.x + threadIdx.x; i < total4; i += gridDim.x * blockDim.x) {
    float4 v = ((const float4*)in)[i];
    ushort4 o;
    o.x = f2bf(v.x); o.y = f2bf(v.y); o.z = f2bf(v.z); o.w = f2bf(v.w);
    ((ushort4*)out)[i] = o;
  }
}

// ---------- one-time weight prep: f32 [k][n] -> bf16 transposed [n][k], XOR-swizzled ----------
__global__ void k_prew(const float* __restrict__ W_s, const float* __restrict__ W_f,
                       unsigned* __restrict__ Wsw) {
  int m = blockIdx.x;                 // 0..2L-1: matrix id (l = m>>1, branch = m&1)
  const float* W = ((m & 1) ? W_f : W_s) + (size_t)(m >> 1) * 128 * 128;
  unsigned* dst = Wsw + (size_t)m * 8192;
  int tid = threadIdx.x;
  #pragma unroll
  for (int p = 0; p < 32; ++p) {
    int idx = p * 256 + tid;          // dword index
    int kp = idx & 63, n = idx >> 6;  // k = 2*kp
    float w0 = W[(2 * kp) * 128 + n];
    float w1 = W[(2 * kp + 1) * 128 + n];
    unsigned pk = (unsigned)f2bf(w0) | ((unsigned)f2bf(w1) << 16);
    unsigned byte = (unsigned)(n * 256 + kp * 4) ^ ((unsigned)(n & 7) << 4);
    *(unsigned*)((char*)dst + byte) = pk;
  }
}

// ---------- MFMA GEMM: C(bf16) = dis[row] * (A(N x 128, bf16) @ W) ----------
__global__ __launch_bounds__(THREADS) void k_gemm_mfma(
    const unsigned short* __restrict__ A,
    const unsigned* __restrict__ Wsw,            // 2 matrices for this layer
    const float* __restrict__ dis_s, const float* __restrict__ dis_f,
    unsigned short* __restrict__ C0, unsigned short* __restrict__ C1, int N) {
  const unsigned* Wm  = Wsw + (size_t)blockIdx.y * 8192;
  const float*    dis = blockIdx.y ? dis_f : dis_s;
  unsigned short* C   = blockIdx.y ? C1 : C0;
  __shared__ unsigned Wt[8192];                  // 32 KiB
  int tid = threadIdx.x;
  #pragma unroll
  for (int i = 0; i < 8; ++i)
    ((float4*)Wt)[i * 256 + tid] = ((const float4*)Wm)[i * 256 + tid];
  __syncthreads();

  int wid = tid >> 6, lane = tid & 63;
  int kg = lane >> 4;                            // 0..3
  int rbase = blockIdx.x * 128 + wid * 32;       // wave covers rows [rbase, rbase+32)
  const unsigned short* arow[2];
  #pragma unroll
  for (int rt = 0; rt < 2; ++rt) {
    int r = rbase + rt * 16 + (lane & 15); if (r > N - 1) r = N - 1;   // clamp; store guarded
    arow[rt] = A + (size_t)r * 128;
  }

  f32x4 acc[2][8];
  #pragma unroll
  for (int rt = 0; rt < 2; ++rt)
    #pragma unroll
    for (int nt = 0; nt < 8; ++nt) acc[rt][nt] = (f32x4){0.f, 0.f, 0.f, 0.f};

  #pragma unroll
  for (int ks = 0; ks < 4; ++ks) {
    s16x8 af0 = *(const s16x8*)(arow[0] + ks * 32 + kg * 8);
    s16x8 af1 = *(const s16x8*)(arow[1] + ks * 32 + kg * 8);
    #pragma unroll
    for (int nt = 0; nt < 8; ++nt) {
      int col = nt * 16 + (lane & 15);
      unsigned byte = (unsigned)(col * 256 + (ks * 32 + kg * 8) * 2) ^ ((unsigned)(col & 7) << 4);
      s16x8 bfrag = *(const s16x8*)((char*)Wt + byte);
      acc[0][nt] = __builtin_amdgcn_mfma_f32_16x16x32_bf16(af0, bfrag, acc[0][nt], 0, 0, 0);
      acc[1][nt] = __builtin_amdgcn_mfma_f32_16x16x32_bf16(af1, bfrag, acc[1][nt], 0, 0, 0);
    }
  }
  // C/D layout (m89): col = lane&15, row = (lane>>4)*4 + reg. Scale row by dis[row].
  #pragma unroll
  for (int rt = 0; rt < 2; ++rt) {
    #pragma unroll
    for (int r = 0; r < 4; ++r) {
      int row = rbase + rt * 16 + kg * 4 + r;
      if (row < N) {
        float d = dis[row];
        #pragma unroll
        for (int nt = 0; nt < 8; ++nt) {
          int col = nt * 16 + (lane & 15);
          C[(size_t)row * 128 + col] = f2bf(acc[rt][nt][r] * d);
        }
      }
    }
  }
}

// ---------- aggregation: agg[v] = dis_s[v]*(t's[v] + Σ w*t's[src]) + dis_f[v]*(...) ----------
__global__ __launch_bounds__(THREADS) void k_gather(
    const unsigned short* __restrict__ t_sc, const unsigned short* __restrict__ t_fc,
    const int* __restrict__ rp8_s, const unsigned* __restrict__ ed_s,
    const int* __restrict__ rp8_f, const unsigned* __restrict__ ed_f,
    const float* __restrict__ dis_s, const float* __restrict__ dis_f,
    float* __restrict__ agg, int N) {
  int gw     = (blockIdx.x * blockDim.x + threadIdx.x) >> 6;
  int lane   = threadIdx.x & 63;
  int nwaves = (gridDim.x * blockDim.x) >> 6;
  for (int v = gw; v < N; v += nwaves) {
    float outx = 0.f, outy = 0.f;
    #pragma unroll 1
    for (int g = 0; g < 2; ++g) {
      const int*            rp = g ? rp8_f : rp8_s;
      const unsigned*       ed = g ? ed_f : ed_s;
      const unsigned short* t  = g ? t_fc : t_sc;
      float                 dv = g ? dis_f[v] : dis_s[v];
      unsigned a = ((const unsigned*)(t + (size_t)v * 128))[lane];
      float ax = bf2f((unsigned short)a);          // self-loop term t'[v]
      float ay = bf2f((unsigned short)(a >> 16));
      int e0 = rp[v * 8], e1 = rp[v * 8 + 8];
      int e = e0;
      for (; e + 7 < e1; e += 8) {          // 8 independent row loads in flight
        unsigned q0 = ed[e],     q1 = ed[e + 1], q2 = ed[e + 2], q3 = ed[e + 3];
        unsigned q4 = ed[e + 4], q5 = ed[e + 5], q6 = ed[e + 6], q7 = ed[e + 7];
        unsigned r0 = ((const unsigned*)(t + (size_t)(q0 & 0xFFFF) * 128))[lane];
        unsigned r1 = ((const unsigned*)(t + (size_t)(q1 & 0xFFFF) * 128))[lane];
        unsigned r2 = ((const unsigned*)(t + (size_t)(q2 & 0xFFFF) * 128))[lane];
        unsigned r3 = ((const unsigned*)(t + (size_t)(q3 & 0xFFFF) * 128))[lane];
        unsigned r4 = ((const unsigned*)(t + (size_t)(q4 & 0xFFFF) * 128))[lane];
        unsigned r5 = ((const unsigned*)(t + (size_t)(q5 & 0xFFFF) * 128))[lane];
        unsigned r6 = ((const unsigned*)(t + (size_t)(q6 & 0xFFFF) * 128))[lane];
        unsigned r7 = ((const unsigned*)(t + (size_t)(q7 & 0xFFFF) * 128))[lane];
        float w0 = bf2f((unsigned short)(q0 >> 16)), w1 = bf2f((unsigned short)(q1 >> 16));
        float w2 = bf2f((unsigned short)(q2 >> 16)), w3 = bf2f((unsigned short)(q3 >> 16));
        float w4 = bf2f((unsigned short)(q4 >> 16)), w5 = bf2f((unsigned short)(q5 >> 16));
        float w6 = bf2f((unsigned short)(q6 >> 16)), w7 = bf2f((unsigned short)(q7 >> 16));
        ax = fmaf(bf2f((unsigned short)r0), w0, ax); ay = fmaf(bf2f((unsigned short)(r0 >> 16)), w0, ay);
        ax = fmaf(bf2f((unsigned short)r1), w1, ax); ay = fmaf(bf2f((unsigned short)(r1 >> 16)), w1, ay);
        ax = fmaf(bf2f((unsigned short)r2), w2, ax); ay = fmaf(bf2f((unsigned short)(r2 >> 16)), w2, ay);
        ax = fmaf(bf2f((unsigned short)r3), w3, ax); ay = fmaf(bf2f((unsigned short)(r3 >> 16)), w3, ay);
        ax = fmaf(bf2f((unsigned short)r4), w4, ax); ay = fmaf(bf2f((unsigned short)(r4 >> 16)), w4, ay);
        ax = fmaf(bf2f((unsigned short)r5), w5, ax); ay = fmaf(bf2f((unsigned short)(r5 >> 16)), w5, ay);
        ax = fmaf(bf2f((unsigned short)r6), w6, ax); ay = fmaf(bf2f((unsigned short)(r6 >> 16)), w6, ay);
        ax = fmaf(bf2f((unsigned short)r7), w7, ax); ay = fmaf(bf2f((unsigned short)(r7 >> 16)), w7, ay);
      }
      for (; e + 1 < e1; e += 2) {
        unsigned q0 = ed[e], q1 = ed[e + 1];
        unsigned r0 = ((const unsigned*)(t + (size_t)(q0 & 0xFFFF) * 128))[lane];
        unsigned r1 = ((const unsigned*)(t + (size_t)(q1 & 0xFFFF) * 128))[lane];
        float w0 = bf2f((unsigned short)(q0 >> 16)), w1 = bf2f((unsigned short)(q1 >> 16));
        ax = fmaf(bf2f((unsigned short)r0), w0, ax); ay = fmaf(bf2f((unsigned short)(r0 >> 16)), w0, ay);
        ax = fmaf(bf2f((unsigned short)r1), w1, ax); ay = fmaf(bf2f((unsigned short)(r1 >> 16)), w1, ay);
      }
      if (e < e1) {
        unsigned q0 = ed[e];
        unsigned r0 = ((const unsigned*)(t + (size_t)(q0 & 0xFFFF) * 128))[lane];
        float w0 = bf2f((unsigned short)(q0 >> 16));
        ax = fmaf(bf2f((unsigned short)r0), w0, ax);
        ay = fmaf(bf2f((unsigned short)(r0 >> 16)), w0, ay);
      }
      outx = fmaf(ax, dv, outx);
      outy = fmaf(ay, dv, outy);
    }
    ((float2*)(agg + (size_t)v * 128))[lane] = make_float2(outx, outy);
  }
}

// ---------- BN stats: per-block partials (no atomics) + reduce ----------
#define SBLK 256
__global__ void k_stats(const float* __restrict__ agg, double* __restrict__ pb, int N) {
  __shared__ double sb[THREADS], qb[THREADS];
  int col  = threadIdx.x & 127;
  int half = threadIdx.x >> 7;
  double s = 0, q = 0;
  for (int r = blockIdx.x * 2 + half; r < N; r += gridDim.x * 2) {
    float v = agg[(size_t)r * 128 + col];
    s += v; q += (double)v * v;
  }
  sb[threadIdx.x] = s; qb[threadIdx.x] = q;
  __syncthreads();
  if (half == 0) {
    pb[(size_t)blockIdx.x * 256 + col]       = sb[threadIdx.x] + sb[threadIdx.x + 128];
    pb[(size_t)blockIdx.x * 256 + 128 + col] = qb[threadIdx.x] + qb[threadIdx.x + 128];
  }
}

__global__ void k_stats2(const double* __restrict__ pb, double* __restrict__ stats) {
  int t = threadIdx.x;   // 256 threads: col = t&127, kind = t>>7
  double s = 0;
  for (int b = 0; b < SBLK; ++b) s += pb[(size_t)b * 256 + t];
  stats[t] = s;
}

// last==0: write bf16 h for next layer's GEMM. last==1: write f32 d_out.
__global__ void k_bn(const float* __restrict__ agg, const double* __restrict__ stats,
                     const float* __restrict__ gamma, const float* __restrict__ beta,
                     unsigned short* __restrict__ outb, float* __restrict__ outf,
                     int N, int last) {
  int total = N * 128;
  double invN = 1.0 / (double)N;
  for (int i = blockIdx.x * blockDim.x + threadIdx.x; i < total; i += gridDim.x * blockDim.x) {
    int c = i & 127;
    double m   = stats[c] * invN;
    double var = stats[128 + c] * invN - m * m;
    float scale = gamma[c] * rsqrtf((float)var + 1e-5f);
    float shift = beta[c] - (float)m * scale;
    float v = fmaf(agg[i], scale, shift);
    v = v > 0.f ? v : 0.f;
    if (last) outf[i] = v;
    else      outb[i] = f2bf(v);
  }
}

extern "C" void kernel_launch(void* const* d_in, const int* in_sizes, int n_in,
                              void* d_out, int out_size, void* d_ws, size_t ws_size,
                              hipStream_t stream) {
  const float* x     = (const float*)d_in[0];
  const int*   ei_s  = (const int*)d_in[1];
  const float* w_s   = (const float*)d_in[2];
  const int*   ei_f  = (const int*)d_in[3];
  const float* w_f   = (const float*)d_in[4];
  const float* W_s   = (const float*)d_in[5];
  const float* W_f   = (const float*)d_in[7];
  const float* gamma = (const float*)d_in[9];
  const float* beta  = (const float*)d_in[10];
  float* out = (float*)d_out;

  const int N = in_sizes[0] / 128;
  const int E = in_sizes[2];
  const int L = in_sizes[5] / (128 * 128);

  char* ws = (char*)d_ws;
  size_t off = 0;
  auto alloc = [&](size_t bytes) -> void* {
    void* p = (void*)(ws + off);
    off += (bytes + 255) & ~(size_t)255;
    return p;
  };
  double* stats = (double*)alloc(256 * sizeof(double));
  double* pb    = (double*)alloc((size_t)SBLK * 256 * sizeof(double));
  unsigned* Wsw = (unsigned*)alloc((size_t)2 * L * 8192 * 4);
  unsigned short* t_sc = (unsigned short*)alloc((size_t)N * 128 * 2);
  unsigned short* t_fc = (unsigned short*)alloc((size_t)N * 128 * 2);
  unsigned short* hb   = (unsigned short*)alloc((size_t)N * 128 * 2);
  float* agg   = (float*)alloc((size_t)N * 128 * 4);
  float* dis_s = (float*)alloc((size_t)N * 4);
  float* dis_f = (float*)alloc((size_t)N * 4);
  int*   rp8_s = (int*)alloc(((size_t)N * NREP + 1) * 4);
  int*   rp8_f = (int*)alloc(((size_t)N * NREP + 1) * 4);
  int*   cur8_s = (int*)alloc((size_t)N * NREP * 4);
  int*   cur8_f = (int*)alloc((size_t)N * NREP * 4);
  int*   cnt8_s = (int*)alloc((size_t)N * NREP * 4);
  int*   cnt8_f = (int*)alloc((size_t)N * NREP * 4);
  unsigned* ed_s = (unsigned*)alloc((size_t)E * 4);
  unsigned* ed_f = (unsigned*)alloc((size_t)E * 4);

  int nb_n = (N + THREADS - 1) / THREADS;                 // 196
  int nb_e = (E + THREADS - 1) / THREADS;                 // 2500
  int nb8  = (N * NREP + THREADS - 1) / THREADS;          // 1563
  int* bsum = (int*)alloc((size_t)2 * nb8 * 4);

  dim3 ge(nb_e, 2), g8(nb8, 2), gn(nb_n, 2);

  // one-time weight prep + CSR/degree build (layer-invariant)
  k_prew<<<2 * L, THREADS, 0, stream>>>(W_s, W_f, Wsw);
  k_init8<<<nb8, THREADS, 0, stream>>>(cnt8_s, cnt8_f, N * NREP);
  k_cnt<<<ge, THREADS, 0, stream>>>(ei_s + E, ei_f + E, cnt8_s, cnt8_f, E, N);
  k_scan1<<<g8, THREADS, 0, stream>>>(cnt8_s, cnt8_f, rp8_s, rp8_f, bsum, N, nb8);
  k_scan2<<<2, THREADS, 0, stream>>>(bsum, nb8);
  k_scan3<<<g8, THREADS, 0, stream>>>(rp8_s, rp8_f, cur8_s, cur8_f, bsum, N, nb8, E);
  k_scatter2<<<ge, THREADS, 0, stream>>>(ei_s, w_s, ei_f, w_f,
                                         cur8_s, cur8_f, ed_s, ed_f, E, N);
  k_deg<<<gn, THREADS, 0, stream>>>(rp8_s, ed_s, rp8_f, ed_f, dis_s, dis_f, N);

  k_cast<<<1024, THREADS, 0, stream>>>(x, hb, N * 128 / 4);

  for (int l = 0; l < L; ++l) {
    dim3 gg((N + 127) / 128, 2);
    k_gemm_mfma<<<gg, THREADS, 0, stream>>>(hb, Wsw + (size_t)l * 2 * 8192,
                                            dis_s, dis_f, t_sc, t_fc, N);
    k_gather<<<2048, THREADS, 0, stream>>>(t_sc, t_fc, rp8_s, ed_s, rp8_f, ed_f,
                                           dis_s, dis_f, agg, N);
    k_stats<<<SBLK, THREADS, 0, stream>>>(agg, pb, N);
    k_stats2<<<1, 256, 0, stream>>>(pb, stats);
    k_bn<<<2048, THREADS, 0, stream>>>(agg, stats, gamma + l * 128, beta + l * 128,
                                       hb, out, N, (l == L - 1) ? 1 : 0);
  }
}

// Round 12
// 309.658 us; speedup vs baseline: 1.3465x; 1.3465x over previous
//
#include <hip/hip_runtime.h>
#include <hip/hip_bf16.h>

#define THREADS 256
#define NBLKA 256          // pass-A blocks per graph (must match hist/scat)
#define CAPB 3072          // pass-B LDS edge capacity (mean bucket = 819)

typedef __attribute__((ext_vector_type(8))) short s16x8;   // 8 bf16 = 4 VGPR
typedef __attribute__((ext_vector_type(4))) float f32x4;

// bf16 helpers (RNE)
static __device__ __forceinline__ unsigned short f2bf(float f) {
  union { float f; unsigned u; } v; v.f = f;
  unsigned r = (v.u + 0x7FFF + ((v.u >> 16) & 1)) >> 16;
  return (unsigned short)r;
}
static __device__ __forceinline__ float bf2f(unsigned short h) {
  union { unsigned u; float f; } v; v.u = ((unsigned)h) << 16;
  return v.f;
}

// ---------- CSR build: two-level counting sort ----------
// Level A histogram: per-(bucket,block) counts, LDS only (no global atomics).
__global__ void k_histA(const int* __restrict__ col_s, const int* __restrict__ col_f,
                        int* __restrict__ hm_s, int* __restrict__ hm_f, int E, int nbk) {
  const int* col = blockIdx.y ? col_f : col_s;
  int*       hm  = blockIdx.y ? hm_f  : hm_s;
  __shared__ int h[1024];
  for (int i = threadIdx.x; i < nbk; i += THREADS) h[i] = 0;
  __syncthreads();
  for (int e = blockIdx.x * THREADS + threadIdx.x; e < E; e += THREADS * NBLKA)
    atomicAdd(&h[col[e] >> 6], 1);
  __syncthreads();
  for (int b = threadIdx.x; b < nbk; b += THREADS) hm[b * NBLKA + blockIdx.x] = h[b];
}

// exclusive scan of the nbk*256 count matrix (3 stages)
__global__ void k_scanA1(const int* __restrict__ hm_s, const int* __restrict__ hm_f,
                         int* __restrict__ sc_s, int* __restrict__ sc_f,
                         int* __restrict__ bsum, int M, int nbk) {
  const int* hm = blockIdx.y ? hm_f : hm_s;
  int*       sc = blockIdx.y ? sc_f : sc_s;
  __shared__ int buf[THREADS];
  int idx = blockIdx.x * THREADS + threadIdx.x;
  int v = (idx < M) ? hm[idx] : 0;
  buf[threadIdx.x] = v;
  __syncthreads();
  #pragma unroll
  for (int off = 1; off < THREADS; off <<= 1) {
    int t = (threadIdx.x >= off) ? buf[threadIdx.x - off] : 0;
    __syncthreads();
    buf[threadIdx.x] += t;
    __syncthreads();
  }
  if (idx < M) sc[idx] = buf[threadIdx.x] - v;
  if (threadIdx.x == THREADS - 1) bsum[blockIdx.y * nbk + blockIdx.x] = buf[THREADS - 1];
}

__global__ void k_scanA2(int* __restrict__ bsum, int nb) {
  int* b = bsum + blockIdx.x * nb;
  __shared__ int buf[THREADS];
  __shared__ int carry;
  if (threadIdx.x == 0) carry = 0;
  __syncthreads();
  for (int base = 0; base < nb; base += THREADS) {
    int i = base + threadIdx.x;
    int v = (i < nb) ? b[i] : 0;
    buf[threadIdx.x] = v;
    __syncthreads();
    #pragma unroll
    for (int off = 1; off < THREADS; off <<= 1) {
      int t = (threadIdx.x >= off) ? buf[threadIdx.x - off] : 0;
      __syncthreads();
      buf[threadIdx.x] += t;
      __syncthreads();
    }
    if (i < nb) b[i] = carry + buf[threadIdx.x] - v;
    __syncthreads();
    if (threadIdx.x == 0) carry += buf[THREADS - 1];
    __syncthreads();
  }
}

__global__ void k_scanA3(int* __restrict__ sc_s, int* __restrict__ sc_f,
                         const int* __restrict__ bsum, int M, int nbk) {
  int* sc = blockIdx.y ? sc_f : sc_s;
  int idx = blockIdx.x * THREADS + threadIdx.x;
  if (idx < M) sc[idx] += bsum[blockIdx.y * nbk + blockIdx.x];
}

// Level A scatter: same edge assignment as k_histA; per-(block,bucket) writes contiguous.
// tmp record: dest(16) | src(16) | bf16(w)(16) in a u64.
__global__ void k_scatA(const int* __restrict__ ei_s, const float* __restrict__ w_s,
                        const int* __restrict__ ei_f, const float* __restrict__ w_f,
                        const int* __restrict__ sc_s, const int* __restrict__ sc_f,
                        unsigned long long* __restrict__ tmp_s,
                        unsigned long long* __restrict__ tmp_f, int E, int nbk) {
  const int*          ei  = blockIdx.y ? ei_f  : ei_s;
  const float*        w   = blockIdx.y ? w_f   : w_s;
  const int*          sc  = blockIdx.y ? sc_f  : sc_s;
  unsigned long long* tmp = blockIdx.y ? tmp_f : tmp_s;
  __shared__ int bas[1024];
  __shared__ int h2[1024];
  for (int b = threadIdx.x; b < nbk; b += THREADS) {
    bas[b] = sc[b * NBLKA + blockIdx.x];
    h2[b] = 0;
  }
  __syncthreads();
  for (int e = blockIdx.x * THREADS + threadIdx.x; e < E; e += THREADS * NBLKA) {
    int c = ei[E + e], r = ei[e];
    int b = c >> 6;
    int rk = atomicAdd(&h2[b], 1);
    tmp[bas[b] + rk] = ((unsigned long long)(unsigned)(c & 0xFFFF) << 32)
                     | ((unsigned long long)(unsigned)(r & 0xFFFF) << 16)
                     | (unsigned long long)f2bf(w[e]);
  }
}

// Level B: per-bucket counting sort in LDS; final ed (src|w<<16), rowptr, dis.
__global__ __launch_bounds__(THREADS) void k_passB(
    const unsigned long long* __restrict__ tmp_s, const unsigned long long* __restrict__ tmp_f,
    const int* __restrict__ sc_s, const int* __restrict__ sc_f,
    unsigned* __restrict__ ed_s, unsigned* __restrict__ ed_f,
    int* __restrict__ rp_s, int* __restrict__ rp_f,
    float* __restrict__ dis_s, float* __restrict__ dis_f, int E, int N, int nbk) {
  const unsigned long long* tmp = blockIdx.y ? tmp_f : tmp_s;
  const int*                sc  = blockIdx.y ? sc_f  : sc_s;
  unsigned*                 ed  = blockIdx.y ? ed_f  : ed_s;
  int*                      rp  = blockIdx.y ? rp_f  : rp_s;
  float*                    dis = blockIdx.y ? dis_f : dis_s;
  int b = blockIdx.x;
  int base = sc[b * NBLKA];
  int next = (b + 1 < nbk) ? sc[(b + 1) * NBLKA] : E;
  int cnt = next - base;
  __shared__ unsigned long long eb[CAPB];
  __shared__ unsigned outb[CAPB];
  __shared__ int h[64], exc[65], h2[64];
  int tid = threadIdx.x;
  if (tid < 64) { h[tid] = 0; h2[tid] = 0; }
  __syncthreads();
  if (cnt <= CAPB) {
    for (int i = tid; i < cnt; i += THREADS) {
      unsigned long long rec = tmp[base + i];
      eb[i] = rec;
      atomicAdd(&h[(int)((rec >> 32) & 63)], 1);
    }
    __syncthreads();
    if (tid == 0) { int a = 0; for (int i = 0; i < 64; ++i) { exc[i] = a; a += h[i]; } exc[64] = a; }
    __syncthreads();
    for (int i = tid; i < cnt; i += THREADS) {
      unsigned long long rec = eb[i];
      int ld = (int)((rec >> 32) & 63);
      int rk = atomicAdd(&h2[ld], 1);
      outb[exc[ld] + rk] = (unsigned)((rec >> 16) & 0xFFFF) | ((unsigned)(rec & 0xFFFF) << 16);
    }
    __syncthreads();
    for (int i = tid; i < cnt; i += THREADS) ed[base + i] = outb[i];
    if (tid < 64) {
      int v = b * 64 + tid;
      if (v < N) {
        rp[v] = base + exc[tid];
        float s = 0.f;
        for (int j = exc[tid]; j < exc[tid + 1]; ++j) s += bf2f((unsigned short)(outb[j] >> 16));
        dis[v] = rsqrtf(1.0f + s);
      }
    }
  } else {   // fallback (statistically unreachable): same algorithm from global
    for (int i = tid; i < cnt; i += THREADS) atomicAdd(&h[(int)((tmp[base + i] >> 32) & 63)], 1);
    __syncthreads();
    if (tid == 0) { int a = 0; for (int i = 0; i < 64; ++i) { exc[i] = a; a += h[i]; } exc[64] = a; }
    __syncthreads();
    for (int i = tid; i < cnt; i += THREADS) {
      unsigned long long rec = tmp[base + i];
      int ld = (int)((rec >> 32) & 63);
      int rk = atomicAdd(&h2[ld], 1);
      ed[base + exc[ld] + rk] = (unsigned)((rec >> 16) & 0xFFFF) | ((unsigned)(rec & 0xFFFF) << 16);
    }
    __syncthreads();
    if (tid < 64) {
      int v = b * 64 + tid;
      if (v < N) {
        rp[v] = base + exc[tid];
        float s = 0.f;
        for (int j = exc[tid]; j < exc[tid + 1]; ++j) s += bf2f((unsigned short)(ed[base + j] >> 16));
        dis[v] = rsqrtf(1.0f + s);
      }
    }
  }
  if (b == 0 && tid == 0) rp[N] = E;
}

// ---------- cast x (f32) -> bf16 ----------
__global__ void k_cast(const float* __restrict__ in, unsigned short* __restrict__ out, int total4) {
  for (int i = blockIdx.x * blockDim.x + threadIdx.x; i < total4; i += gridDim.x * blockDim.x) {
    float4 v = ((const float4*)in)[i];
    ushort4 o;
    o.x = f2bf(v.x); o.y = f2bf(v.y); o.z = f2bf(v.z); o.w = f2bf(v.w);
    ((ushort4*)out)[i] = o;
  }
}

// ---------- one-time weight prep: f32 [k][n] -> bf16 transposed [n][k], XOR-swizzled ----------
__global__ void k_prew(const float* __restrict__ W_s, const float* __restrict__ W_f,
                       unsigned* __restrict__ Wsw) {
  int m = blockIdx.x;                 // 0..2L-1: matrix id (l = m>>1, branch = m&1)
  const float* W = ((m & 1) ? W_f : W_s) + (size_t)(m >> 1) * 128 * 128;
  unsigned* dst = Wsw + (size_t)m * 8192;
  int tid = threadIdx.x;
  #pragma unroll
  for (int p = 0; p < 32; ++p) {
    int idx = p * 256 + tid;          // dword index
    int kp = idx & 63, n = idx >> 6;  // k = 2*kp
    float w0 = W[(2 * kp) * 128 + n];
    float w1 = W[(2 * kp + 1) * 128 + n];
    unsigned pk = (unsigned)f2bf(w0) | ((unsigned)f2bf(w1) << 16);
    unsigned byte = (unsigned)(n * 256 + kp * 4) ^ ((unsigned)(n & 7) << 4);
    *(unsigned*)((char*)dst + byte) = pk;
  }
}

// ---------- MFMA GEMM: C(bf16) = dis[row] * (A(N x 128, bf16) @ W) ----------
__global__ __launch_bounds__(THREADS) void k_gemm_mfma(
    const unsigned short* __restrict__ A,
    const unsigned* __restrict__ Wsw,            // 2 matrices for this layer
    const float* __restrict__ dis_s, const float* __restrict__ dis_f,
    unsigned short* __restrict__ C0, unsigned short* __restrict__ C1, int N) {
  const unsigned* Wm  = Wsw + (size_t)blockIdx.y * 8192;
  const float*    dis = blockIdx.y ? dis_f : dis_s;
  unsigned short* C   = blockIdx.y ? C1 : C0;
  __shared__ unsigned Wt[8192];                  // 32 KiB
  int tid = threadIdx.x;
  #pragma unroll
  for (int i = 0; i < 8; ++i)
    ((float4*)Wt)[i * 256 + tid] = ((const float4*)Wm)[i * 256 + tid];
  __syncthreads();

  int wid = tid >> 6, lane = tid & 63;
  int kg = lane >> 4;                            // 0..3
  int rbase = blockIdx.x * 128 + wid * 32;       // wave covers rows [rbase, rbase+32)
  const unsigned short* arow[2];
  #pragma unroll
  for (int rt = 0; rt < 2; ++rt) {
    int r = rbase + rt * 16 + (lane & 15); if (r > N - 1) r = N - 1;   // clamp; store guarded
    arow[rt] = A + (size_t)r * 128;
  }

  f32x4 acc[2][8];
  #pragma unroll
  for (int rt = 0; rt < 2; ++rt)
    #pragma unroll
    for (int nt = 0; nt < 8; ++nt) acc[rt][nt] = (f32x4){0.f, 0.f, 0.f, 0.f};

  #pragma unroll
  for (int ks = 0; ks < 4; ++ks) {
    s16x8 af0 = *(const s16x8*)(arow[0] + ks * 32 + kg * 8);
    s16x8 af1 = *(const s16x8*)(arow[1] + ks * 32 + kg * 8);
    #pragma unroll
    for (int nt = 0; nt < 8; ++nt) {
      int col = nt * 16 + (lane & 15);
      unsigned byte = (unsigned)(col * 256 + (ks * 32 + kg * 8) * 2) ^ ((unsigned)(col & 7) << 4);
      s16x8 bfrag = *(const s16x8*)((char*)Wt + byte);
      acc[0][nt] = __builtin_amdgcn_mfma_f32_16x16x32_bf16(af0, bfrag, acc[0][nt], 0, 0, 0);
      acc[1][nt] = __builtin_amdgcn_mfma_f32_16x16x32_bf16(af1, bfrag, acc[1][nt], 0, 0, 0);
    }
  }
  // C/D layout (m89): col = lane&15, row = (lane>>4)*4 + reg. Scale row by dis[row].
  #pragma unroll
  for (int rt = 0; rt < 2; ++rt) {
    #pragma unroll
    for (int r = 0; r < 4; ++r) {
      int row = rbase + rt * 16 + kg * 4 + r;
      if (row < N) {
        float d = dis[row];
        #pragma unroll
        for (int nt = 0; nt < 8; ++nt) {
          int col = nt * 16 + (lane & 15);
          C[(size_t)row * 128 + col] = f2bf(acc[rt][nt][r] * d);
        }
      }
    }
  }
}

// ---------- aggregation: agg[v] = dis_s[v]*(t's[v] + Σ w*t's[src]) + dis_f[v]*(...) ----------
__global__ __launch_bounds__(THREADS) void k_gather(
    const unsigned short* __restrict__ t_sc, const unsigned short* __restrict__ t_fc,
    const int* __restrict__ rp_s, const unsigned* __restrict__ ed_s,
    const int* __restrict__ rp_f, const unsigned* __restrict__ ed_f,
    const float* __restrict__ dis_s, const float* __restrict__ dis_f,
    float* __restrict__ agg, int N) {
  int gw     = (blockIdx.x * blockDim.x + threadIdx.x) >> 6;
  int lane   = threadIdx.x & 63;
  int nwaves = (gridDim.x * blockDim.x) >> 6;
  for (int v = gw; v < N; v += nwaves) {
    float outx = 0.f, outy = 0.f;
    #pragma unroll 1
    for (int g = 0; g < 2; ++g) {
      const int*            rp = g ? rp_f : rp_s;
      const unsigned*       ed = g ? ed_f : ed_s;
      const unsigned short* t  = g ? t_fc : t_sc;
      float                 dv = g ? dis_f[v] : dis_s[v];
      unsigned a = ((const unsigned*)(t + (size_t)v * 128))[lane];
      float ax = bf2f((unsigned short)a);          // self-loop term t'[v]
      float ay = bf2f((unsigned short)(a >> 16));
      int e0 = rp[v], e1 = rp[v + 1];
      int e = e0;
      for (; e + 7 < e1; e += 8) {          // 8 independent row loads in flight
        unsigned q0 = ed[e],     q1 = ed[e + 1], q2 = ed[e + 2], q3 = ed[e + 3];
        unsigned q4 = ed[e + 4], q5 = ed[e + 5], q6 = ed[e + 6], q7 = ed[e + 7];
        unsigned r0 = ((const unsigned*)(t + (size_t)(q0 & 0xFFFF) * 128))[lane];
        unsigned r1 = ((const unsigned*)(t + (size_t)(q1 & 0xFFFF) * 128))[lane];
        unsigned r2 = ((const unsigned*)(t + (size_t)(q2 & 0xFFFF) * 128))[lane];
        unsigned r3 = ((const unsigned*)(t + (size_t)(q3 & 0xFFFF) * 128))[lane];
        unsigned r4 = ((const unsigned*)(t + (size_t)(q4 & 0xFFFF) * 128))[lane];
        unsigned r5 = ((const unsigned*)(t + (size_t)(q5 & 0xFFFF) * 128))[lane];
        unsigned r6 = ((const unsigned*)(t + (size_t)(q6 & 0xFFFF) * 128))[lane];
        unsigned r7 = ((const unsigned*)(t + (size_t)(q7 & 0xFFFF) * 128))[lane];
        float w0 = bf2f((unsigned short)(q0 >> 16)), w1 = bf2f((unsigned short)(q1 >> 16));
        float w2 = bf2f((unsigned short)(q2 >> 16)), w3 = bf2f((unsigned short)(q3 >> 16));
        float w4 = bf2f((unsigned short)(q4 >> 16)), w5 = bf2f((unsigned short)(q5 >> 16));
        float w6 = bf2f((unsigned short)(q6 >> 16)), w7 = bf2f((unsigned short)(q7 >> 16));
        ax = fmaf(bf2f((unsigned short)r0), w0, ax); ay = fmaf(bf2f((unsigned short)(r0 >> 16)), w0, ay);
        ax = fmaf(bf2f((unsigned short)r1), w1, ax); ay = fmaf(bf2f((unsigned short)(r1 >> 16)), w1, ay);
        ax = fmaf(bf2f((unsigned short)r2), w2, ax); ay = fmaf(bf2f((unsigned short)(r2 >> 16)), w2, ay);
        ax = fmaf(bf2f((unsigned short)r3), w3, ax); ay = fmaf(bf2f((unsigned short)(r3 >> 16)), w3, ay);
        ax = fmaf(bf2f((unsigned short)r4), w4, ax); ay = fmaf(bf2f((unsigned short)(r4 >> 16)), w4, ay);
        ax = fmaf(bf2f((unsigned short)r5), w5, ax); ay = fmaf(bf2f((unsigned short)(r5 >> 16)), w5, ay);
        ax = fmaf(bf2f((unsigned short)r6), w6, ax); ay = fmaf(bf2f((unsigned short)(r6 >> 16)), w6, ay);
        ax = fmaf(bf2f((unsigned short)r7), w7, ax); ay = fmaf(bf2f((unsigned short)(r7 >> 16)), w7, ay);
      }
      for (; e + 1 < e1; e += 2) {
        unsigned q0 = ed[e], q1 = ed[e + 1];
        unsigned r0 = ((const unsigned*)(t + (size_t)(q0 & 0xFFFF) * 128))[lane];
        unsigned r1 = ((const unsigned*)(t + (size_t)(q1 & 0xFFFF) * 128))[lane];
        float w0 = bf2f((unsigned short)(q0 >> 16)), w1 = bf2f((unsigned short)(q1 >> 16));
        ax = fmaf(bf2f((unsigned short)r0), w0, ax); ay = fmaf(bf2f((unsigned short)(r0 >> 16)), w0, ay);
        ax = fmaf(bf2f((unsigned short)r1), w1, ax); ay = fmaf(bf2f((unsigned short)(r1 >> 16)), w1, ay);
      }
      if (e < e1) {
        unsigned q0 = ed[e];
        unsigned r0 = ((const unsigned*)(t + (size_t)(q0 & 0xFFFF) * 128))[lane];
        float w0 = bf2f((unsigned short)(q0 >> 16));
        ax = fmaf(bf2f((unsigned short)r0), w0, ax);
        ay = fmaf(bf2f((unsigned short)(r0 >> 16)), w0, ay);
      }
      outx = fmaf(ax, dv, outx);
      outy = fmaf(ay, dv, outy);
    }
    ((float2*)(agg + (size_t)v * 128))[lane] = make_float2(outx, outy);
  }
}

// ---------- BN stats: per-block partials (no atomics) + reduce ----------
#define SBLK 256
__global__ void k_stats(const float* __restrict__ agg, double* __restrict__ pb, int N) {
  __shared__ double sb[THREADS], qb[THREADS];
  int col  = threadIdx.x & 127;
  int half = threadIdx.x >> 7;
  double s = 0, q = 0;
  for (int r = blockIdx.x * 2 + half; r < N; r += gridDim.x * 2) {
    float v = agg[(size_t)r * 128 + col];
    s += v; q += (double)v * v;
  }
  sb[threadIdx.x] = s; qb[threadIdx.x] = q;
  __syncthreads();
  if (half == 0) {
    pb[(size_t)blockIdx.x * 256 + col]       = sb[threadIdx.x] + sb[threadIdx.x + 128];
    pb[(size_t)blockIdx.x * 256 + 128 + col] = qb[threadIdx.x] + qb[threadIdx.x + 128];
  }
}

__global__ void k_stats2(const double* __restrict__ pb, double* __restrict__ stats) {
  int t = threadIdx.x;   // 256 threads: col = t&127, kind = t>>7
  double s = 0;
  for (int b = 0; b < SBLK; ++b) s += pb[(size_t)b * 256 + t];
  stats[t] = s;
}

// last==0: write bf16 h for next layer's GEMM. last==1: write f32 d_out.
__global__ void k_bn(const float* __restrict__ agg, const double* __restrict__ stats,
                     const float* __restrict__ gamma, const float* __restrict__ beta,
                     unsigned short* __restrict__ outb, float* __restrict__ outf,
                     int N, int last) {
  int total = N * 128;
  double invN = 1.0 / (double)N;
  for (int i = blockIdx.x * blockDim.x + threadIdx.x; i < total; i += gridDim.x * blockDim.x) {
    int c = i & 127;
    double m   = stats[c] * invN;
    double var = stats[128 + c] * invN - m * m;
    float scale = gamma[c] * rsqrtf((float)var + 1e-5f);
    float shift = beta[c] - (float)m * scale;
    float v = fmaf(agg[i], scale, shift);
    v = v > 0.f ? v : 0.f;
    if (last) outf[i] = v;
    else      outb[i] = f2bf(v);
  }
}

extern "C" void kernel_launch(void* const* d_in, const int* in_sizes, int n_in,
                              void* d_out, int out_size, void* d_ws, size_t ws_size,
                              hipStream_t stream) {
  const float* x     = (const float*)d_in[0];
  const int*   ei_s  = (const int*)d_in[1];
  const float* w_s   = (const float*)d_in[2];
  const int*   ei_f  = (const int*)d_in[3];
  const float* w_f   = (const float*)d_in[4];
  const float* W_s   = (const float*)d_in[5];
  const float* W_f   = (const float*)d_in[7];
  const float* gamma = (const float*)d_in[9];
  const float* beta  = (const float*)d_in[10];
  float* out = (float*)d_out;

  const int N = in_sizes[0] / 128;
  const int E = in_sizes[2];
  const int L = in_sizes[5] / (128 * 128);
  const int nbk = (N + 63) >> 6;            // 782 coarse buckets (64 vertices each)
  const int M = nbk * NBLKA;                // count-matrix size per graph

  char* ws = (char*)d_ws;
  size_t off = 0;
  auto alloc = [&](size_t bytes) -> void* {
    void* p = (void*)(ws + off);
    off += (bytes + 255) & ~(size_t)255;
    return p;
  };
  double* stats = (double*)alloc(256 * sizeof(double));
  double* pb    = (double*)alloc((size_t)SBLK * 256 * sizeof(double));
  unsigned* Wsw = (unsigned*)alloc((size_t)2 * L * 8192 * 4);
  unsigned short* t_sc = (unsigned short*)alloc((size_t)N * 128 * 2);
  unsigned short* t_fc = (unsigned short*)alloc((size_t)N * 128 * 2);
  unsigned short* hb   = (unsigned short*)alloc((size_t)N * 128 * 2);
  float* agg   = (float*)alloc((size_t)N * 128 * 4);
  float* dis_s = (float*)alloc((size_t)N * 4);
  float* dis_f = (float*)alloc((size_t)N * 4);
  int*   rp_s  = (int*)alloc((size_t)(N + 1) * 4);
  int*   rp_f  = (int*)alloc((size_t)(N + 1) * 4);
  int*   hm_s  = (int*)alloc((size_t)M * 4);
  int*   hm_f  = (int*)alloc((size_t)M * 4);
  int*   sc_s  = (int*)alloc((size_t)M * 4);
  int*   sc_f  = (int*)alloc((size_t)M * 4);
  unsigned long long* tmp_s = (unsigned long long*)alloc((size_t)E * 8);
  unsigned long long* tmp_f = (unsigned long long*)alloc((size_t)E * 8);
  unsigned* ed_s = (unsigned*)alloc((size_t)E * 4);
  unsigned* ed_f = (unsigned*)alloc((size_t)E * 4);
  int* bsum = (int*)alloc((size_t)2 * nbk * 4);

  dim3 ga(NBLKA, 2), gm(nbk, 2);

  // one-time weight prep + CSR/degree build (layer-invariant)
  k_prew<<<2 * L, THREADS, 0, stream>>>(W_s, W_f, Wsw);
  k_histA<<<ga, THREADS, 0, stream>>>(ei_s + E, ei_f + E, hm_s, hm_f, E, nbk);
  k_scanA1<<<gm, THREADS, 0, stream>>>(hm_s, hm_f, sc_s, sc_f, bsum, M, nbk);
  k_scanA2<<<2, THREADS, 0, stream>>>(bsum, nbk);
  k_scanA3<<<gm, THREADS, 0, stream>>>(sc_s, sc_f, bsum, M, nbk);
  k_scatA<<<ga, THREADS, 0, stream>>>(ei_s, w_s, ei_f, w_f, sc_s, sc_f, tmp_s, tmp_f, E, nbk);
  k_passB<<<gm, THREADS, 0, stream>>>(tmp_s, tmp_f, sc_s, sc_f, ed_s, ed_f,
                                      rp_s, rp_f, dis_s, dis_f, E, N, nbk);

  k_cast<<<1024, THREADS, 0, stream>>>(x, hb, N * 128 / 4);

  for (int l = 0; l < L; ++l) {
    dim3 gg((N + 127) / 128, 2);
    k_gemm_mfma<<<gg, THREADS, 0, stream>>>(hb, Wsw + (size_t)l * 2 * 8192,
                                            dis_s, dis_f, t_sc, t_fc, N);
    k_gather<<<2048, THREADS, 0, stream>>>(t_sc, t_fc, rp_s, ed_s, rp_f, ed_f,
                                           dis_s, dis_f, agg, N);
    k_stats<<<SBLK, THREADS, 0, stream>>>(agg, pb, N);
    k_stats2<<<1, 256, 0, stream>>>(pb, stats);
    k_bn<<<2048, THREADS, 0, stream>>>(agg, stats, gamma + l * 128, beta + l * 128,
                                       hb, out, N, (l == L - 1) ? 1 : 0);
  }
}